// Round 5
// baseline (267.081 us; speedup 1.0000x reference)
//
#include <hip/hip_runtime.h>

// Shapes fixed by setup_inputs():
#define BB    8
#define CF    256
#define HF    128
#define WF    128
#define HLBL  512
#define WLBL  512
#define COLD  16
#define NCLS  21
#define PSTR  260   // padded LDS stride (multiple of 4 -> 16B-aligned rows)
#define WHALF 64    // pixels per block (w-split: 2 blocks per feature row)
#define NBLK  (BB * HF * 2)

// Accumulator bins in a module-scope device global (R3): zero-initialized at
// load, re-zeroed by proto_loss_final after reading (idempotent under graph
// replay). Kernel-boundary release/acquire provides coherence -- R2 proved
// per-block __threadfence costs ~200 us on multi-XCD CDNA4.
__device__ float g_bins[32];   // [0..16) class sums, [16..32) class counts

__global__ __launch_bounds__(256) void proto_loss_main(
    const float* __restrict__ outputs_old,   // [B, COLD, HL, WL]
    const float* __restrict__ features,      // [B, CF, HF, WF]
    const int*   __restrict__ labels,        // [B, HL, WL]
    const float* __restrict__ prototypes)    // [NCLS, CF]
{
    // ids = argmax over COLD=16 channels -> ids in [0,16). Only 16 proto rows needed.
    __shared__ float sproto[COLD * PSTR];    // 16.6 KB
    __shared__ float spartial[4][WHALF];     // 1 KB (per-wave quartet sums)
    __shared__ int   sids[WHALF];
    __shared__ float ssum[16];
    __shared__ float scnt[16];
    // total ~18 KB -> 8 blocks/CU (grid 2048 = 8/CU; was 4/CU, 34% occupancy)

    const int t    = threadIdx.x;
    const int blk  = blockIdx.x;             // 0 .. 2*B*HF-1
    const int b    = blk >> 8;               // / (HF*2)
    const int rest = blk & 255;
    const int h    = rest >> 1;              // feature row
    const int w0   = (rest & 1) * WHALF;     // row half

    // stage prototype rows 0..15 as float4 (1024 float4 / 256 threads = 4 each)
    #pragma unroll
    for (int i = t; i < COLD * (CF / 4); i += 256) {
        const int r  = i >> 6;               // / (CF/4)
        const int c4 = (i & 63) << 2;
        *(float4*)&sproto[r * PSTR + c4] =
            *(const float4*)&prototypes[r * CF + c4];
    }
    if (t < 16) { ssum[t] = 0.0f; scnt[t] = 0.0f; }

    // per-pixel pseudo-class ids (nearest-down: src = (4h, 4(w0+t)))
    if (t < WHALF) {
        const int w = w0 + t;
        int id = 0;
        const int lab = labels[(b * HLBL + h * 4) * WLBL + w * 4];
        if (lab == 0) {
            const float* po = outputs_old
                + ((size_t)b * COLD * HLBL + (size_t)h * 4) * WLBL + w * 4;
            float best = po[0];
            #pragma unroll
            for (int c = 1; c < COLD; ++c) {
                float v = po[(size_t)c * HLBL * WLBL];
                if (v > best) { best = v; id = c; }   // strict >: first-max tie-break
            }
        }
        sids[t] = id;
    }
    __syncthreads();

    // Phase 2: 16 groups of 4 pixels x 16 channel phases. Lanes l, l+16, l+32,
    // l+48 of a wave share a group (s = t&15) and hold 4 consecutive c-phases,
    // so the activity guard is uniform within each shuffle quartet.
    // Class-0 bin is dropped by the reference (per_class[1:]): all-id0 groups
    // skip loads entirely (exec-masked: no VMEM issued).
    const int s     = t & 15;                // pixel group 0..15
    const int c_off = t >> 4;                // channel phase 0..15
    const int w4    = s * 4;                 // local pixel base
    const int id0 = sids[w4 + 0];
    const int id1 = sids[w4 + 1];
    const int id2 = sids[w4 + 2];
    const int id3 = sids[w4 + 3];

    if ((id0 | id1 | id2 | id3) != 0) {
        const float* pr0 = &sproto[id0 * PSTR];
        const float* pr1 = &sproto[id1 * PSTR];
        const float* pr2 = &sproto[id2 * PSTR];
        const float* pr3 = &sproto[id3 * PSTR];
        const float* fbase = features
            + ((size_t)b * CF * HF + h) * WF + w0 + w4;

        float a0 = 0.f, a1 = 0.f, a2 = 0.f, a3 = 0.f;
        #pragma unroll 8
        for (int k = 0; k < 16; ++k) {
            const int c = k * 16 + c_off;
            const float4 f = *(const float4*)(fbase + (size_t)c * (HF * WF));
            float d0 = f.x - pr0[c]; a0 += d0 * d0;
            float d1 = f.y - pr1[c]; a1 += d1 * d1;
            float d2 = f.z - pr2[c]; a2 += d2 * d2;
            float d3 = f.w - pr3[c]; a3 += d3 * d3;
        }
        // quartet reduce: sum lanes {l, l+16, l+32, l+48} -> lanes l<16
        a0 += __shfl_down(a0, 32); a0 += __shfl_down(a0, 16);
        a1 += __shfl_down(a1, 32); a1 += __shfl_down(a1, 16);
        a2 += __shfl_down(a2, 32); a2 += __shfl_down(a2, 16);
        a3 += __shfl_down(a3, 32); a3 += __shfl_down(a3, 16);
        if ((t & 48) == 0) {                 // lane < 16 within its wave
            const int wv = t >> 6;           // wave 0..3
            spartial[wv][w4 + 0] = a0;
            spartial[wv][w4 + 1] = a1;
            spartial[wv][w4 + 2] = a2;
            spartial[wv][w4 + 3] = a3;
        }
    }
    __syncthreads();

    // Phase 3: per-pixel value -> per-class LDS bins (id==0 pixels skipped;
    // spartial entries of inactive groups are stale but never read)
    if (t < WHALF) {
        const int id = sids[t];
        if (id != 0) {
            float pp = spartial[0][t] + spartial[1][t]
                     + spartial[2][t] + spartial[3][t];
            pp *= (1.0f / CF);
            atomicAdd(&ssum[id], pp);
            atomicAdd(&scnt[id], 1.0f);
        }
    }
    __syncthreads();

    // Tail: per-block bins -> device-scope atomics (proven-cheap in R0/R3)
    if (t < 32) {
        const float v = (t < 16) ? ssum[t] : scnt[t - 16];
        if (v != 0.f) atomicAdd(&g_bins[t], v);
    }
}

__global__ void proto_loss_final(const int* __restrict__ classes_old,
                                 const int* __restrict__ inc_step,
                                 float* __restrict__ out)
{
    __shared__ float sfin[32];
    const int t = threadIdx.x;

    if (t < 32) sfin[t] = g_bins[t];   // visible: kernel-boundary acquire
    __syncthreads();

    if (t == 0) {
        float r = 0.0f;
        if (*inc_step != 0) {
            int K = *classes_old;
            if (K > 16) K = 16;
            for (int id = 1; id < K; ++id) {
                const float cnt = sfin[16 + id];
                if (cnt > 0.f) r += sfin[id] / cnt;
            }
        }
        out[0] = r;
    }

    // re-zero for the next launch / graph replay (idempotence)
    if (t < 32) g_bins[t] = 0.0f;
}

extern "C" void kernel_launch(void* const* d_in, const int* in_sizes, int n_in,
                              void* d_out, int out_size, void* d_ws, size_t ws_size,
                              hipStream_t stream)
{
    const float* outputs_old = (const float*)d_in[1];
    const float* features    = (const float*)d_in[2];
    const int*   labels      = (const int*)d_in[4];
    const float* prototypes  = (const float*)d_in[5];
    const int*   classes_old = (const int*)d_in[6];
    const int*   inc_step    = (const int*)d_in[7];

    proto_loss_main<<<dim3(NBLK), dim3(256), 0, stream>>>(
        outputs_old, features, labels, prototypes);
    proto_loss_final<<<dim3(1), dim3(64), 0, stream>>>(
        classes_old, inc_step, (float*)d_out);
}

// Round 6
// 261.014 us; speedup vs baseline: 1.0232x; 1.0232x over previous
//
#include <hip/hip_runtime.h>

// Shapes fixed by setup_inputs():
#define BB    8
#define CF    256
#define HF    128
#define WF    128
#define HLBL  512
#define WLBL  512
#define COLD  16
#define NCLS  21
#define PSTR  260   // padded LDS stride (multiple of 4 -> 16B-aligned rows)
#define NBLK  (BB * HF)
#define NSLOT 8     // bin slots; blk&7 ~= XCD id under default round-robin dispatch

// Accumulator bins in a module-scope device global (R3): zero-initialized at
// load, re-zeroed by proto_loss_final after reading (idempotent under graph
// replay). Kernel-boundary release/acquire provides coherence (R2: per-block
// __threadfence = serialized L2 writebacks, +200us).
// NSLOT slots spread the same-line RMW contention: 1024 block-tails hammering
// ONE 128B bin region bounce its lines across 8 non-coherent XCD L2s; with
// blk&7 slotting, each slot's lines are touched by (mostly) one XCD.
__device__ float g_bins[NSLOT][32];   // [s][0..16) sums, [s][16..32) counts

__global__ __launch_bounds__(256) void proto_loss_main(
    const float* __restrict__ outputs_old,   // [B, COLD, HL, WL]
    const float* __restrict__ features,      // [B, CF, HF, WF]
    const int*   __restrict__ labels,        // [B, HL, WL]
    const float* __restrict__ prototypes)    // [NCLS, CF]
{
    // ids = argmax over COLD=16 channels -> ids in [0,16). Only 16 proto rows needed.
    __shared__ float sproto[COLD * PSTR];    // 16.6 KB
    __shared__ float spartial[8][WF];        // 4 KB
    __shared__ int   sids[WF];
    __shared__ float ssum[16];
    __shared__ float scnt[16];

    const int t   = threadIdx.x;
    const int blk = blockIdx.x;              // 0 .. B*HF-1
    const int b   = blk >> 7;                // / HF
    const int h   = blk & (HF - 1);          // % HF

    // Phase 1 FIRST: labels load + argmax gather head the critical path;
    // issue them before the prototype staging loads.
    // per-pixel pseudo-class ids (nearest-down: src = (4h, 4w))
    if (t < WF) {
        const int w = t;
        int id = 0;
        const int lab = labels[(b * HLBL + h * 4) * WLBL + w * 4];
        if (lab == 0) {
            const float* po = outputs_old
                + ((size_t)b * COLD * HLBL + (size_t)h * 4) * WLBL + w * 4;
            float best = po[0];
            #pragma unroll
            for (int c = 1; c < COLD; ++c) {
                float v = po[(size_t)c * HLBL * WLBL];
                if (v > best) { best = v; id = c; }   // strict >: first-max tie-break
            }
        }
        sids[w] = id;
    }

    // stage prototype rows 0..15 as float4 (1024 float4 / 256 threads = 4 each)
    #pragma unroll
    for (int i = t; i < COLD * (CF / 4); i += 256) {
        const int r  = i >> 6;               // / (CF/4)
        const int c4 = (i & 63) << 2;
        *(float4*)&sproto[r * PSTR + c4] =
            *(const float4*)&prototypes[r * CF + c4];
    }
    if (t < 16) { ssum[t] = 0.0f; scnt[t] = 0.0f; }
    __syncthreads();

    // Phase 2: float4 feature loads. thread -> 4 consecutive w, 8 c-slices/iter.
    // Lanes 0..31 of a wave cover consecutive w4 at one c_off -> coalesced
    // masked loads (R1's compaction broke this; do not reorder lanes).
    // Class-0 bin is dropped by the reference (per_class[1:]), so threads whose
    // 4 pixels are ALL id==0 skip their loads entirely (exec-masked: no VMEM).
    const int w4    = (t & 31) * 4;
    const int c_off = t >> 5;                // 0..7
    const int id0 = sids[w4 + 0];
    const int id1 = sids[w4 + 1];
    const int id2 = sids[w4 + 2];
    const int id3 = sids[w4 + 3];

    float a0 = 0.f, a1 = 0.f, a2 = 0.f, a3 = 0.f;
    if ((id0 | id1 | id2 | id3) != 0) {
        const float* pr0 = &sproto[id0 * PSTR];
        const float* pr1 = &sproto[id1 * PSTR];
        const float* pr2 = &sproto[id2 * PSTR];
        const float* pr3 = &sproto[id3 * PSTR];
        const float* fbase = features + ((size_t)b * CF * HF + h) * WF + w4;

        #pragma unroll 8
        for (int k = 0; k < 32; ++k) {
            const int c = k * 8 + c_off;
            const float4 f = *(const float4*)(fbase + (size_t)c * (HF * WF));
            float d0 = f.x - pr0[c]; a0 += d0 * d0;
            float d1 = f.y - pr1[c]; a1 += d1 * d1;
            float d2 = f.z - pr2[c]; a2 += d2 * d2;
            float d3 = f.w - pr3[c]; a3 += d3 * d3;
        }
    }
    spartial[c_off][w4 + 0] = a0;
    spartial[c_off][w4 + 1] = a1;
    spartial[c_off][w4 + 2] = a2;
    spartial[c_off][w4 + 3] = a3;
    __syncthreads();

    // Phase 3: per-pixel value -> per-class LDS bins (id==0 pixels skipped;
    // spartial for their groups may be stale, but is never read)
    if (t < WF) {
        const int id = sids[t];
        if (id != 0) {
            float pp = 0.f;
            #pragma unroll
            for (int co = 0; co < 8; ++co) pp += spartial[co][t];
            pp *= (1.0f / CF);
            atomicAdd(&ssum[id], pp);
            atomicAdd(&scnt[id], 1.0f);
        }
    }
    __syncthreads();

    // Tail: per-block bins -> slotted device atomics (contention spread 8x)
    if (t < 32) {
        const float v = (t < 16) ? ssum[t] : scnt[t - 16];
        if (v != 0.f) atomicAdd(&g_bins[blk & (NSLOT - 1)][t], v);
    }
}

__global__ void proto_loss_final(const int* __restrict__ classes_old,
                                 const int* __restrict__ inc_step,
                                 float* __restrict__ out)
{
    __shared__ float sfin[32];
    const int t = threadIdx.x;

    if (t < 32) {
        float v = 0.f;
        #pragma unroll
        for (int s = 0; s < NSLOT; ++s) v += g_bins[s][t];
        sfin[t] = v;
    }
    __syncthreads();

    if (t == 0) {
        float r = 0.0f;
        if (*inc_step != 0) {
            int K = *classes_old;
            if (K > 16) K = 16;
            for (int id = 1; id < K; ++id) {
                const float cnt = sfin[16 + id];
                if (cnt > 0.f) r += sfin[id] / cnt;
            }
        }
        out[0] = r;
    }

    // re-zero all slots for the next launch / graph replay (idempotence)
    for (int i = t; i < NSLOT * 32; i += 64)
        ((float*)g_bins)[i] = 0.0f;
}

extern "C" void kernel_launch(void* const* d_in, const int* in_sizes, int n_in,
                              void* d_out, int out_size, void* d_ws, size_t ws_size,
                              hipStream_t stream)
{
    const float* outputs_old = (const float*)d_in[1];
    const float* features    = (const float*)d_in[2];
    const int*   labels      = (const int*)d_in[4];
    const float* prototypes  = (const float*)d_in[5];
    const int*   classes_old = (const int*)d_in[6];
    const int*   inc_step    = (const int*)d_in[7];

    proto_loss_main<<<dim3(NBLK), dim3(256), 0, stream>>>(
        outputs_old, features, labels, prototypes);
    proto_loss_final<<<dim3(1), dim3(64), 0, stream>>>(
        classes_old, inc_step, (float*)d_out);
}